// Round 7
// baseline (8051.493 us; speedup 1.0000x reference)
//
#include <hip/hip_runtime.h>
#include <float.h>

#define QN 8
#define KN 1024
#define DN 64
#define MARGIN 1e-2f

// XLA-GPU (ROCm wave64) row-reduce emulation for sum of squares over n=64:
//   p_t = round(a_t * a_t)  (elementwise mul materialized first)
//   warp shuffle-down halving tree: offsets 32,16,8,4,2,1:
//     L1_t = p_t + p_{t+32}; L2_t = L1_t + L1_{t+16}; ... ; total = L5_0 + L5_1
// Every op individually rounded (__f*_rn pins rounding, defeats contraction).
__device__ __forceinline__ float np_sumsq64(const float* a) {
    float p[DN];
    #pragma unroll
    for (int t = 0; t < DN; ++t) p[t] = __fmul_rn(a[t], a[t]);
    float l1[32];
    #pragma unroll
    for (int t = 0; t < 32; ++t) l1[t] = __fadd_rn(p[t], p[t + 32]);
    float l2[16];
    #pragma unroll
    for (int t = 0; t < 16; ++t) l2[t] = __fadd_rn(l1[t], l1[t + 16]);
    float l3[8];
    #pragma unroll
    for (int t = 0; t < 8; ++t) l3[t] = __fadd_rn(l2[t], l2[t + 8]);
    float l4[4];
    #pragma unroll
    for (int t = 0; t < 4; ++t) l4[t] = __fadd_rn(l3[t], l3[t + 4]);
    const float l5a = __fadd_rn(l4[0], l4[2]);
    const float l5b = __fadd_rn(l4[1], l4[3]);
    return __fadd_rn(l5a, l5b);
}

// One thread per input vector.
// Reference-exact fp32 state: q accumulated with single __fadd_rn per stage,
// r = x (-) q re-derived each stage. Fast expansion scan (top-3) + near-tie
// rescore emulating the reference executed by XLA on the ROCm GPU:
//   rr, cn : wave64 butterfly tree of rounded squares (np_sumsq64)
//   cross  : sequential fp32 FMA chain over d (rocBLAS/Tensile v_fmac k-order)
//   d2     : (rr (-) 2*cross) (+) cn, each op rounded
//   argmin : min with lower index on ties (first occurrence)
__global__ __launch_bounds__(256) void rvq_encode_kernel(
    const float* __restrict__ x,
    const float* __restrict__ cb,
    float* __restrict__ out_enc,   // [N, Q] indices written as float
    float* __restrict__ out_q)     // [N, D] quantized
{
    __shared__ float cnorm[QN * KN];   // 32 KiB, butterfly-tree ||c||^2

    for (int c = threadIdx.x; c < QN * KN; c += blockDim.x) {
        float row[DN];
        const float4* cp = reinterpret_cast<const float4*>(cb + (size_t)c * DN);
        #pragma unroll
        for (int d4 = 0; d4 < DN / 4; ++d4) {
            float4 v = cp[d4];
            row[4 * d4 + 0] = v.x;
            row[4 * d4 + 1] = v.y;
            row[4 * d4 + 2] = v.z;
            row[4 * d4 + 3] = v.w;
        }
        cnorm[c] = np_sumsq64(row);
    }
    __syncthreads();

    const int i = blockIdx.x * blockDim.x + threadIdx.x;
    const float* xrow = x + (size_t)i * DN;

    float q[DN];
    #pragma unroll
    for (int d = 0; d < DN; ++d) q[d] = 0.f;

    int code[QN];

    #pragma unroll 1
    for (int j = 0; j < QN; ++j) {
        const float* cbj = cb + (size_t)j * KN * DN;
        const float* cn  = &cnorm[j * KN];

        // ---- reference-exact residual: r = x (-) q ----
        float r[DN];
        {
            const float4* xr = reinterpret_cast<const float4*>(xrow);
            #pragma unroll
            for (int d4 = 0; d4 < DN / 4; ++d4) {
                float4 v = xr[d4];
                r[4 * d4 + 0] = __fsub_rn(v.x, q[4 * d4 + 0]);
                r[4 * d4 + 1] = __fsub_rn(v.y, q[4 * d4 + 1]);
                r[4 * d4 + 2] = __fsub_rn(v.z, q[4 * d4 + 2]);
                r[4 * d4 + 3] = __fsub_rn(v.w, q[4 * d4 + 3]);
            }
        }

        // ---- rr in butterfly-tree order (used by scan AND rescore) ----
        const float rr = np_sumsq64(r);

        // ---- fast top-3 scan ----
        float b1 = FLT_MAX, b2 = FLT_MAX, b3 = FLT_MAX;
        int   i1 = 0, i2 = 0, i3 = 0;

        #pragma unroll 2
        for (int k = 0; k < KN; ++k) {
            const float4* cp = reinterpret_cast<const float4*>(cbj + (size_t)k * DN);
            float a0 = 0.f, a1 = 0.f, a2 = 0.f, a3 = 0.f;
            #pragma unroll
            for (int d4 = 0; d4 < DN / 4; ++d4) {
                float4 v = cp[d4];
                a0 = fmaf(r[4 * d4 + 0], v.x, a0);
                a1 = fmaf(r[4 * d4 + 1], v.y, a1);
                a2 = fmaf(r[4 * d4 + 2], v.z, a2);
                a3 = fmaf(r[4 * d4 + 3], v.w, a3);
            }
            const float dot = (a0 + a1) + (a2 + a3);
            const float d2  = (rr - 2.0f * dot) + cn[k];

            const bool lt1 = d2 < b1;
            const bool lt2 = d2 < b2;
            const bool lt3 = d2 < b3;
            b3 = lt2 ? b2 : (lt3 ? d2 : b3);
            i3 = lt2 ? i2 : (lt3 ? k  : i3);
            b2 = lt1 ? b1 : (lt2 ? d2 : b2);
            i2 = lt1 ? i1 : (lt2 ? k  : i2);
            b1 = lt1 ? d2 : b1;
            i1 = lt1 ? k  : i1;
        }

        int chosen = i1;

        // ---- near-tie rescore: XLA-GPU fp32 expansion emulation ----
        if (b2 - b1 < MARGIN) {
            const float* c0p = cbj + (size_t)i1 * DN;
            const float* c1p = cbj + (size_t)i2 * DN;
            const float* c2p = cbj + (size_t)i3 * DN;

            float cr0 = 0.f, cr1 = 0.f, cr2 = 0.f;
            #pragma unroll 1
            for (int d = 0; d < DN; ++d) {
                cr0 = __fmaf_rn(r[d], c0p[d], cr0);
                cr1 = __fmaf_rn(r[d], c1p[d], cr1);
                cr2 = __fmaf_rn(r[d], c2p[d], cr2);
            }
            const float d2c0 = __fadd_rn(__fsub_rn(rr, __fmul_rn(2.0f, cr0)), cn[i1]);
            const float d2c1 = __fadd_rn(__fsub_rn(rr, __fmul_rn(2.0f, cr1)), cn[i2]);
            const float d2c2 = __fadd_rn(__fsub_rn(rr, __fmul_rn(2.0f, cr2)), cn[i3]);

            float bd = d2c0; int bk = i1;
            if (d2c1 < bd || (d2c1 == bd && i2 < bk)) { bd = d2c1; bk = i2; }
            if (d2c2 < bd || (d2c2 == bd && i3 < bk)) { bd = d2c2; bk = i3; }
            chosen = bk;
        }

        code[j] = chosen;
        out_enc[(size_t)i * QN + j] = (float)chosen;

        // ---- reference-exact quantized update: q = q (+) cb[chosen] ----
        const float4* cw = reinterpret_cast<const float4*>(cbj + (size_t)chosen * DN);
        #pragma unroll
        for (int d4 = 0; d4 < DN / 4; ++d4) {
            float4 v = cw[d4];
            q[4 * d4 + 0] = __fadd_rn(q[4 * d4 + 0], v.x);
            q[4 * d4 + 1] = __fadd_rn(q[4 * d4 + 1], v.y);
            q[4 * d4 + 2] = __fadd_rn(q[4 * d4 + 2], v.z);
            q[4 * d4 + 3] = __fadd_rn(q[4 * d4 + 3], v.w);
        }
    }

    // ---- quantized output: q is already reference-exact ----
    {
        float4* qo = reinterpret_cast<float4*>(out_q + (size_t)i * DN);
        #pragma unroll
        for (int d4 = 0; d4 < DN / 4; ++d4) {
            float4 o;
            o.x = q[4 * d4 + 0];
            o.y = q[4 * d4 + 1];
            o.z = q[4 * d4 + 2];
            o.w = q[4 * d4 + 3];
            qo[d4] = o;
        }
    }
}

extern "C" void kernel_launch(void* const* d_in, const int* in_sizes, int n_in,
                              void* d_out, int out_size, void* d_ws, size_t ws_size,
                              hipStream_t stream) {
    const float* x  = (const float*)d_in[0];
    const float* cb = (const float*)d_in[1];
    const int n = in_sizes[0] / DN;

    float* out_enc = (float*)d_out;                     // [N, Q]
    float* out_q   = (float*)d_out + (size_t)n * QN;    // [N, D]

    dim3 block(256);
    dim3 grid((n + 255) / 256);
    rvq_encode_kernel<<<grid, block, 0, stream>>>(x, cb, out_enc, out_q);
}

// Round 8
// 7288.955 us; speedup vs baseline: 1.1046x; 1.1046x over previous
//
#include <hip/hip_runtime.h>
#include <float.h>

#define QN 8
#define KN 1024
#define DN 64
#define MARGIN 1e-2f

// ===================== FROZEN reference-emulation machinery =====================
// (validated round 7: absmax = 0 vs harness np reference)
// XLA-GPU (ROCm wave64) row-reduce: p_t = round(a_t*a_t); halving butterfly
// tree offsets 32,16,8,4,2,1. Every op individually rounded.
__device__ __forceinline__ float np_sumsq64(const float* a) {
    float p[DN];
    #pragma unroll
    for (int t = 0; t < DN; ++t) p[t] = __fmul_rn(a[t], a[t]);
    float l1[32];
    #pragma unroll
    for (int t = 0; t < 32; ++t) l1[t] = __fadd_rn(p[t], p[t + 32]);
    float l2[16];
    #pragma unroll
    for (int t = 0; t < 16; ++t) l2[t] = __fadd_rn(l1[t], l1[t + 16]);
    float l3[8];
    #pragma unroll
    for (int t = 0; t < 8; ++t) l3[t] = __fadd_rn(l2[t], l2[t + 8]);
    float l4[4];
    #pragma unroll
    for (int t = 0; t < 4; ++t) l4[t] = __fadd_rn(l3[t], l3[t + 4]);
    const float l5a = __fadd_rn(l4[0], l4[2]);
    const float l5b = __fadd_rn(l4[1], l4[3]);
    return __fadd_rn(l5a, l5b);
}

// Reference-exact residual element: r_d = x_d (-) sum(+)_{l<j} cb[l][code_l][d]
// (single fp32 add per stage, then one subtract — bit-equal to the reference's
// quantized/residual cascade; equivalence of inline rebuild vs register carry
// established r3==r5.)
__device__ __forceinline__ float ref_res(const float* __restrict__ xrow,
                                         const float* __restrict__ cb,
                                         const int* code, int j, int d) {
    float qd = 0.f;
    #pragma unroll 1
    for (int l = 0; l < j; ++l)
        qd = __fadd_rn(qd, cb[((size_t)l * KN + code[l]) * DN + d]);
    return __fsub_rn(xrow[d], qd);
}
// ===============================================================================

// One thread per input vector, SLIM persistent state:
//   r[64]   : drifted fp32 residual (plain subtract update) — scan only
//   code[8] : chosen indices
// No persistent q[] => no AGPR parking => 4 waves/SIMD instead of 2.
// Scan ranks s = cn[k] - 2*dot (rr is row-constant, ordering identical).
// Near-ties (gap < MARGIN >> drift+scan noise) go to the frozen exact rescore,
// which rebuilds the reference residual from codes.
__global__ __launch_bounds__(256) void rvq_encode_kernel(
    const float* __restrict__ x,
    const float* __restrict__ cb,
    float* __restrict__ out_enc,   // [N, Q] indices written as float
    float* __restrict__ out_q)     // [N, D] quantized
{
    __shared__ float cnorm[QN * KN];   // 32 KiB, butterfly-tree ||c||^2

    for (int c = threadIdx.x; c < QN * KN; c += blockDim.x) {
        float row[DN];
        const float4* cp = reinterpret_cast<const float4*>(cb + (size_t)c * DN);
        #pragma unroll
        for (int d4 = 0; d4 < DN / 4; ++d4) {
            float4 v = cp[d4];
            row[4 * d4 + 0] = v.x;
            row[4 * d4 + 1] = v.y;
            row[4 * d4 + 2] = v.z;
            row[4 * d4 + 3] = v.w;
        }
        cnorm[c] = np_sumsq64(row);
    }
    __syncthreads();

    const int i = blockIdx.x * blockDim.x + threadIdx.x;
    const float* xrow = x + (size_t)i * DN;

    float r[DN];
    {
        const float4* xr = reinterpret_cast<const float4*>(xrow);
        #pragma unroll
        for (int d4 = 0; d4 < DN / 4; ++d4) {
            float4 v = xr[d4];
            r[4 * d4 + 0] = v.x;
            r[4 * d4 + 1] = v.y;
            r[4 * d4 + 2] = v.z;
            r[4 * d4 + 3] = v.w;
        }
    }

    int code[QN];

    #pragma unroll 1
    for (int j = 0; j < QN; ++j) {
        const float* cbj = cb + (size_t)j * KN * DN;
        const float* cn  = &cnorm[j * KN];

        // ---- fast top-3 scan on s = cn - 2*dot ----
        float b1 = FLT_MAX, b2 = FLT_MAX, b3 = FLT_MAX;
        int   i1 = 0, i2 = 0, i3 = 0;

        #pragma unroll 2
        for (int k = 0; k < KN; ++k) {
            const float4* cp = reinterpret_cast<const float4*>(cbj + (size_t)k * DN);
            float a0 = 0.f, a1 = 0.f, a2 = 0.f, a3 = 0.f;
            #pragma unroll
            for (int d4 = 0; d4 < DN / 4; ++d4) {
                float4 v = cp[d4];
                a0 = fmaf(r[4 * d4 + 0], v.x, a0);
                a1 = fmaf(r[4 * d4 + 1], v.y, a1);
                a2 = fmaf(r[4 * d4 + 2], v.z, a2);
                a3 = fmaf(r[4 * d4 + 3], v.w, a3);
            }
            const float dot = (a0 + a1) + (a2 + a3);
            const float s   = fmaf(-2.0f, dot, cn[k]);

            const bool lt1 = s < b1;
            const bool lt2 = s < b2;
            const bool lt3 = s < b3;
            b3 = lt2 ? b2 : (lt3 ? s : b3);
            i3 = lt2 ? i2 : (lt3 ? k : i3);
            b2 = lt1 ? b1 : (lt2 ? s : b2);
            i2 = lt1 ? i1 : (lt2 ? k : i2);
            b1 = lt1 ? s : b1;
            i1 = lt1 ? k : i1;
        }

        int chosen = i1;

        // ---- near-tie rescore: FROZEN exact emulation (rebuilt residual) ----
        if (b2 - b1 < MARGIN) {
            // rr via butterfly tree over reference-exact residual
            float l1[32];
            #pragma unroll 1
            for (int t = 0; t < 32; ++t) {
                const float ra = ref_res(xrow, cb, code, j, t);
                const float rb = ref_res(xrow, cb, code, j, t + 32);
                l1[t] = __fadd_rn(__fmul_rn(ra, ra), __fmul_rn(rb, rb));
            }
            float l2[16];
            #pragma unroll
            for (int t = 0; t < 16; ++t) l2[t] = __fadd_rn(l1[t], l1[t + 16]);
            float l3[8];
            #pragma unroll
            for (int t = 0; t < 8; ++t) l3[t] = __fadd_rn(l2[t], l2[t + 8]);
            float l4[4];
            #pragma unroll
            for (int t = 0; t < 4; ++t) l4[t] = __fadd_rn(l3[t], l3[t + 4]);
            const float rr = __fadd_rn(__fadd_rn(l4[0], l4[2]),
                                       __fadd_rn(l4[1], l4[3]));

            // sequential-FMA cross terms against exact residual
            const float* c0p = cbj + (size_t)i1 * DN;
            const float* c1p = cbj + (size_t)i2 * DN;
            const float* c2p = cbj + (size_t)i3 * DN;
            float cr0 = 0.f, cr1 = 0.f, cr2 = 0.f;
            #pragma unroll 1
            for (int d = 0; d < DN; ++d) {
                const float rd = ref_res(xrow, cb, code, j, d);
                cr0 = __fmaf_rn(rd, c0p[d], cr0);
                cr1 = __fmaf_rn(rd, c1p[d], cr1);
                cr2 = __fmaf_rn(rd, c2p[d], cr2);
            }
            const float d2c0 = __fadd_rn(__fsub_rn(rr, __fmul_rn(2.0f, cr0)), cn[i1]);
            const float d2c1 = __fadd_rn(__fsub_rn(rr, __fmul_rn(2.0f, cr1)), cn[i2]);
            const float d2c2 = __fadd_rn(__fsub_rn(rr, __fmul_rn(2.0f, cr2)), cn[i3]);

            float bd = d2c0; int bk = i1;
            if (d2c1 < bd || (d2c1 == bd && i2 < bk)) { bd = d2c1; bk = i2; }
            if (d2c2 < bd || (d2c2 == bd && i3 < bk)) { bd = d2c2; bk = i3; }
            chosen = bk;
        }

        code[j] = chosen;
        out_enc[(size_t)i * QN + j] = (float)chosen;

        // ---- drifted residual update (scan only; exactness via rebuild) ----
        const float4* cw = reinterpret_cast<const float4*>(cbj + (size_t)chosen * DN);
        #pragma unroll
        for (int d4 = 0; d4 < DN / 4; ++d4) {
            float4 v = cw[d4];
            r[4 * d4 + 0] -= v.x;
            r[4 * d4 + 1] -= v.y;
            r[4 * d4 + 2] -= v.z;
            r[4 * d4 + 3] -= v.w;
        }
    }

    // ---- quantized output: reference-exact q rebuilt from codes ----
    {
        float4* qo = reinterpret_cast<float4*>(out_q + (size_t)i * DN);
        #pragma unroll 1
        for (int d4 = 0; d4 < DN / 4; ++d4) {
            float q0 = 0.f, q1 = 0.f, q2 = 0.f, q3 = 0.f;
            #pragma unroll
            for (int l = 0; l < QN; ++l) {
                const float4 v = *reinterpret_cast<const float4*>(
                    cb + ((size_t)l * KN + code[l]) * DN + 4 * d4);
                q0 = __fadd_rn(q0, v.x);
                q1 = __fadd_rn(q1, v.y);
                q2 = __fadd_rn(q2, v.z);
                q3 = __fadd_rn(q3, v.w);
            }
            float4 o; o.x = q0; o.y = q1; o.z = q2; o.w = q3;
            qo[d4] = o;
        }
    }
}

extern "C" void kernel_launch(void* const* d_in, const int* in_sizes, int n_in,
                              void* d_out, int out_size, void* d_ws, size_t ws_size,
                              hipStream_t stream) {
    const float* x  = (const float*)d_in[0];
    const float* cb = (const float*)d_in[1];
    const int n = in_sizes[0] / DN;

    float* out_enc = (float*)d_out;                     // [N, Q]
    float* out_q   = (float*)d_out + (size_t)n * QN;    // [N, D]

    dim3 block(256);
    dim3 grid((n + 255) / 256);
    rvq_encode_kernel<<<grid, block, 0, stream>>>(x, cb, out_enc, out_q);
}